// Round 16
// baseline (115.201 us; speedup 1.0000x reference)
//
#include <hip/hip_runtime.h>
#include <hip/hip_bf16.h>
#include <math.h>

typedef float f32x4 __attribute__((ext_vector_type(4)));
typedef __bf16 bf16x8 __attribute__((ext_vector_type(8)));
typedef __bf16 bf16x4 __attribute__((ext_vector_type(4)));
typedef unsigned u32x4 __attribute__((ext_vector_type(4)));

#define DEVFN static __device__ __forceinline__

DEVFN void gload16(const void* g, void* l) {
  __builtin_amdgcn_global_load_lds(
      (const __attribute__((address_space(1))) unsigned int*)g,
      (__attribute__((address_space(3))) unsigned int*)l, 16, 0, 0);
}

DEVFN f32x4 mfma16(bf16x8 a, bf16x8 b, f32x4 c) {
  return __builtin_amdgcn_mfma_f32_16x16x32_bf16(a, b, c, 0, 0, 0);
}

DEVFN unsigned cvtpk(float lo, float hi) {
  unsigned r;
  asm("v_cvt_pk_bf16_f32 %0, %1, %2" : "=v"(r) : "v"(lo), "v"(hi));
  return r;
}

#define WAITV4() asm volatile("s_waitcnt vmcnt(4)" ::: "memory")
#define WAITV2() asm volatile("s_waitcnt vmcnt(2)" ::: "memory")
#define WAITV0() asm volatile("s_waitcnt vmcnt(0)" ::: "memory")

// ---- kernel: transpose+cast x [B,C,S] f32 -> xt [B,S,C] bf16, + weight cast --
__global__ __launch_bounds__(256) void transpose_x_k(
    const float* __restrict__ x, __bf16* __restrict__ xt,
    const float* __restrict__ wp, const float* __restrict__ wo,
    __bf16* __restrict__ wpb, __bf16* __restrict__ wob) {
  __shared__ float tile[64][65];
  int b = blockIdx.z, c0 = blockIdx.y * 64, s0 = blockIdx.x * 64;
  int t = threadIdx.x;
  int r = t >> 2, q = (t & 3) << 4;
  const float* src = x + ((size_t)(b * 512 + c0 + r)) * 1024 + s0 + q;
#pragma unroll
  for (int i = 0; i < 4; i++) {
    float4 f = *reinterpret_cast<const float4*>(src + i * 4);
    tile[r][q + i * 4 + 0] = f.x;
    tile[r][q + i * 4 + 1] = f.y;
    tile[r][q + i * 4 + 2] = f.z;
    tile[r][q + i * 4 + 3] = f.w;
  }
  // fused weight cast (independent of the transpose; 2 elems/thread)
  int lid = (blockIdx.z * 8 + blockIdx.y) * 16 + blockIdx.x;  // 0..2047
  int wi = lid * 512 + t * 2;
  if (wi < 786432) {
    float2 f = *reinterpret_cast<const float2*>(wp + wi);
    wpb[wi] = (__bf16)f.x;
    wpb[wi + 1] = (__bf16)f.y;
  } else {
    int j = wi - 786432;
    float2 f = *reinterpret_cast<const float2*>(wo + j);
    wob[j] = (__bf16)f.x;
    wob[j + 1] = (__bf16)f.y;
  }
  __syncthreads();
  bf16x8 o0, o1;
#pragma unroll
  for (int i = 0; i < 8; i++) o0[i] = (__bf16)tile[q + i][r];
#pragma unroll
  for (int i = 0; i < 8; i++) o1[i] = (__bf16)tile[q + 8 + i][r];
  __bf16* dst = xt + ((size_t)(b * 1024 + s0 + r)) * 512 + c0 + q;
  *reinterpret_cast<bf16x8*>(dst) = o0;
  *reinterpret_cast<bf16x8*>(dst + 8) = o1;
}

// ---------------- GEMM1 (QKV): 3-slot rotating pipeline (round-12 verified) ---
// Homogeneous global_load_lds queue; counted vmcnt(4) never 0 mid-loop.
template <int MODE>
__global__ __launch_bounds__(256, 4) void gemm_bt_k(
    const __bf16* __restrict__ A, const __bf16* __restrict__ Bt,
    float* __restrict__ Cf, const float* __restrict__ Xres,
    __bf16* __restrict__ Qo, __bf16* __restrict__ Ko, __bf16* __restrict__ Vto) {
  __shared__ __attribute__((aligned(16))) char smem[49152];  // 3 x (A 8K | B 8K)
  int p = blockIdx.x, xcd = p & 7, idx = p >> 3;
  int m0, n0, z;
  if (MODE == 2) {           // 1536 blocks: m 128 panels, n 12
    m0 = (xcd * 16 + idx / 12) * 128;
    n0 = (idx % 12) * 128;
    z = 0;
  } else {                   // 512 blocks: z 16, m 4, n 8
    z = xcd * 2 + idx / 32;
    int rem = idx % 32;
    m0 = (rem >> 3) * 128;
    n0 = (rem & 7) * 128;
    Bt += (size_t)z * (1024L * 512);
  }
  int tid = threadIdx.x, wave = tid >> 6, lane = tid & 63;
  int fr = lane & 15, fq = lane >> 4;
  int wm = (wave >> 1) * 64, wn = (wave & 1) * 64;
  f32x4 acc[4][4] = {};
  int offs[2], rr[2], scc[2];
#pragma unroll
  for (int i = 0; i < 2; i++) {
    offs[i] = wave * 2048 + i * 1024 + lane * 16;  // 0..8191
    rr[i] = offs[i] >> 6;
    scc[i] = (offs[i] & 63) ^ (((rr[i] ^ (rr[i] >> 2)) & 3) << 4);
  }
  int rdsw = (fr ^ (fr >> 2)) & 3;
  const char* Ap = (const char*)A;
  const char* Bp = (const char*)Bt;

#define GSTAGE(k0_, slot_)                                                      \
  {                                                                             \
    char* as_ = smem + (slot_)*16384;                                           \
    char* bs_ = as_ + 8192;                                                     \
    _Pragma("unroll") for (int i = 0; i < 2; i++)                               \
        gload16(Ap + (size_t)(m0 + rr[i]) * 1024 + (k0_)*2 + scc[i],            \
                as_ + offs[i]);                                                 \
    _Pragma("unroll") for (int i = 0; i < 2; i++)                               \
        gload16(Bp + (size_t)(n0 + rr[i]) * 1024 + (k0_)*2 + scc[i],            \
                bs_ + offs[i]);                                                 \
  }

  GSTAGE(0, 0);
  GSTAGE(32, 1);
#pragma unroll
  for (int t = 0; t < 16; t++) {
    if (t < 15) WAITV4(); else WAITV0();
    __builtin_amdgcn_s_barrier();
    __builtin_amdgcn_sched_barrier(0);
    const char* as = smem + (t % 3) * 16384;
    const char* bs = as + 8192;
    bf16x8 af[4], bfr[4];
#pragma unroll
    for (int mi = 0; mi < 4; mi++)
      af[mi] = *reinterpret_cast<const bf16x8*>(
          as + (wm + mi * 16 + fr) * 64 + ((fq ^ rdsw) << 4));
#pragma unroll
    for (int ni = 0; ni < 4; ni++)
      bfr[ni] = *reinterpret_cast<const bf16x8*>(
          bs + (wn + ni * 16 + fr) * 64 + ((fq ^ rdsw) << 4));
    if (t + 2 < 16) GSTAGE((t + 2) * 32, (t + 2) % 3);
    __builtin_amdgcn_s_setprio(1);
#pragma unroll
    for (int mi = 0; mi < 4; mi++)
#pragma unroll
      for (int ni = 0; ni < 4; ni++)
        acc[mi][ni] = mfma16(af[mi], bfr[ni], acc[mi][ni]);
    __builtin_amdgcn_s_setprio(0);
  }
#undef GSTAGE

  if (MODE == 1) {
    float* Co = Cf + (size_t)z * (512L * 1024);
    const float* Xr = Xres + (size_t)z * (512L * 1024);
#pragma unroll
    for (int mi = 0; mi < 4; mi++)
#pragma unroll
      for (int i = 0; i < 4; i++) {
        int row = m0 + wm + mi * 16 + fq * 4 + i;
#pragma unroll
        for (int ni = 0; ni < 4; ni++) {
          size_t idxo = (size_t)row * 1024 + n0 + wn + ni * 16 + fr;
          Co[idxo] = acc[mi][ni][i] + Xr[idxo];
        }
      }
  } else {
    // ---- fused pixnorm epilogue ----
    int g0 = n0 + wn;            // 64-aligned global output-channel base
    int head = g0 / 192;         // 0..7
    int grp = (g0 >> 6) % 3;     // 0=q, 1=k, 2=v
    int b = m0 >> 10, sb = m0 & 1023;
    int bh = b * 8 + head;
    float nrm[4][4];
#pragma unroll
    for (int mi = 0; mi < 4; mi++)
#pragma unroll
      for (int i = 0; i < 4; i++) {
        float ss = 0.f;
#pragma unroll
        for (int ni = 0; ni < 4; ni++) ss += acc[mi][ni][i] * acc[mi][ni][i];
#pragma unroll
        for (int off = 1; off < 16; off <<= 1) ss += __shfl_xor(ss, off);
        float nv = rsqrtf(ss * (1.0f / 64.0f) + 1e-8f);
        // fold SCALE^2 = 1/8 and log2(e) into Q (attention works in exp2 domain)
        if (grp == 0) nv *= 0.18033688011112042f;
        nrm[mi][i] = nv;
      }
    if (grp < 2) {
      __bf16* dst = (grp == 0 ? Qo : Ko) + (size_t)bh * 65536;
#pragma unroll
      for (int mi = 0; mi < 4; mi++)
#pragma unroll
        for (int i = 0; i < 4; i++) {
          int s = sb + wm + mi * 16 + fq * 4 + i;
#pragma unroll
          for (int ni = 0; ni < 4; ni++)
            dst[(size_t)s * 64 + ni * 16 + fr] = (__bf16)(acc[mi][ni][i] * nrm[mi][i]);
        }
    }
    __syncthreads();
    if (grp == 2) {
      // normalized V -> LDS transpose tile [128 s][64 d], 4B-granule XOR swizzle
#pragma unroll
      for (int mi = 0; mi < 4; mi++)
#pragma unroll
        for (int i = 0; i < 4; i++) {
          int r = wm + mi * 16 + fq * 4 + i;
#pragma unroll
          for (int ni = 0; ni < 4; ni++) {
            int col2 = (2 * (ni * 16 + fr)) ^ ((r & 31) << 2);
            *(__bf16*)(smem + r * 128 + col2) = (__bf16)(acc[mi][ni][i] * nrm[mi][i]);
          }
        }
    }
    __syncthreads();
    if (grp == 2) {
      int sl = wm + lane;  // this wave's 64-s half of the 128-s tile
      // permuted k-order within each 64-s tile: k = a*16+f*4+r stored at f*16+a*4+r
      int l = sl & 63;
      int pl = ((l >> 2) & 3) * 16 + (l >> 4) * 4 + (l & 3);
      __bf16* vdst = Vto + (size_t)bh * 65536 + sb + (sl & 64) + pl;
#pragma unroll 8
      for (int d = 0; d < 64; d++) {
        __bf16 v = *(const __bf16*)(smem + sl * 128 + ((2 * d) ^ ((sl & 31) << 2)));
        vdst[(size_t)d * 1024] = v;
      }
    }
  }
}

// ---- GEMM2 (output): 8-wave 512-thread blocks, 128x128 tile, 2-slot vmcnt(2) -
__global__ __launch_bounds__(512, 4) void gemm_out_k(
    const __bf16* __restrict__ A, const __bf16* __restrict__ Bt,
    float* __restrict__ Cf, const float* __restrict__ Xres) {
  __shared__ __attribute__((aligned(16))) char smem[32768];  // 2 x (A 8K | B 8K)
  const int K = 512;
  int p = blockIdx.x, xcd = p & 7, idx = p >> 3;
  int z = xcd * 2 + idx / 32;
  int rem = idx % 32;
  int m0 = (rem >> 3) * 128;
  int n0 = (rem & 7) * 128;
  Bt += (size_t)z * (1024L * 512);
  int tid = threadIdx.x, wave = tid >> 6, lane = tid & 63;
  int fr = lane & 15, fq = lane >> 4;
  int wm = (wave >> 2) * 64, wn = (wave & 3) * 32;
  f32x4 acc[4][2] = {};
  int offs = tid * 16;           // 0..8191
  int rr = offs >> 6;
  int scc = (offs & 63) ^ (((rr ^ (rr >> 2)) & 3) << 4);
  int rdsw = (fr ^ (fr >> 2)) & 3;
  const char* Ap = (const char*)A;
  const char* Bp = (const char*)Bt;

#define GSTAGE2(k0_, slot_)                                                     \
  {                                                                             \
    char* as_ = smem + (slot_)*16384;                                           \
    gload16(Ap + (size_t)(m0 + rr) * 1024 + (k0_)*2 + scc, as_ + offs);         \
    gload16(Bp + (size_t)(n0 + rr) * 1024 + (k0_)*2 + scc, as_ + 8192 + offs);  \
  }

  GSTAGE2(0, 0);
  GSTAGE2(32, 1);
  int cur = 0;
  for (int k0 = 0; k0 < K; k0 += 32) {
    if (k0 + 32 < K) WAITV2(); else WAITV0();
    __builtin_amdgcn_s_barrier();
    __builtin_amdgcn_sched_barrier(0);
    const char* as = smem + cur * 16384;
    const char* bs = as + 8192;
    bf16x8 af[4], bfr[2];
#pragma unroll
    for (int mi = 0; mi < 4; mi++)
      af[mi] = *reinterpret_cast<const bf16x8*>(
          as + (wm + mi * 16 + fr) * 64 + ((fq ^ rdsw) << 4));
#pragma unroll
    for (int ni = 0; ni < 2; ni++)
      bfr[ni] = *reinterpret_cast<const bf16x8*>(
          bs + (wn + ni * 16 + fr) * 64 + ((fq ^ rdsw) << 4));
    __builtin_amdgcn_s_setprio(1);
#pragma unroll
    for (int mi = 0; mi < 4; mi++)
#pragma unroll
      for (int ni = 0; ni < 2; ni++)
        acc[mi][ni] = mfma16(af[mi], bfr[ni], acc[mi][ni]);
    __builtin_amdgcn_s_setprio(0);
    __builtin_amdgcn_s_barrier();   // all waves done reading slot cur
    if (k0 + 64 < K) GSTAGE2(k0 + 64, cur);
    cur ^= 1;
  }
#undef GSTAGE2

  float* Co = Cf + (size_t)z * (512L * 1024);
  const float* Xr = Xres + (size_t)z * (512L * 1024);
#pragma unroll
  for (int mi = 0; mi < 4; mi++)
#pragma unroll
    for (int i = 0; i < 4; i++) {
      int row = m0 + wm + mi * 16 + fq * 4 + i;
#pragma unroll
      for (int ni = 0; ni < 2; ni++) {
        size_t idxo = (size_t)row * 1024 + n0 + wn + ni * 16 + fr;
        Co[idxo] = acc[mi][ni][i] + Xr[idxo];
      }
    }
}

// ------------- flash attention: QBLK=256 (4 q-sets/wave), 3-slot pipeline -----
__global__ __launch_bounds__(256, 2) void attn_k(const __bf16* __restrict__ Q,
                                                 const __bf16* __restrict__ Kb,
                                                 const __bf16* __restrict__ Vt,
                                                 __bf16* __restrict__ Res) {
  __shared__ __attribute__((aligned(16))) char lds[49152];  // 3 x (K 8K | V 8K)
  int p = blockIdx.x;                    // 512 = 128 bh * 4 qt
  int v = (p & 7) * 64 + (p >> 3);       // XCD cluster: 16 bh per XCD (KV 4MB L2)
  int qt = v & 3, bh = v >> 2;
  int wave = threadIdx.x >> 6, lane = threadIdx.x & 63;
  int fr = lane & 15, fq = lane >> 4;
  const __bf16* Qb = Q + (size_t)bh * 65536;
  const char* Kbase = (const char*)(Kb + (size_t)bh * 65536);
  const char* Vbase = (const char*)(Vt + (size_t)bh * 65536);
  bf16x8 qf[4][2];
#pragma unroll
  for (int qs = 0; qs < 4; qs++)
#pragma unroll
    for (int kk = 0; kk < 2; kk++)
      qf[qs][kk] = *reinterpret_cast<const bf16x8*>(
          Qb + (size_t)(qt * 256 + qs * 64 + wave * 16 + fr) * 64 + kk * 32 + fq * 8);

  bf16x8 ones;
#pragma unroll
  for (int j = 0; j < 8; j++) ones[j] = (__bf16)1.0f;

  f32x4 oa[4][4] = {};
  f32x4 lacc[4] = {};

  int o0 = wave * 2048 + lane * 16;
  int o1 = o0 + 1024;
  int r0 = o0 >> 7, c0 = o0 & 127, r1 = o1 >> 7, c1 = o1 & 127;
  int s0 = c0 ^ ((r0 & 7) << 4), s1 = c1 ^ ((r1 & 7) << 4);
  int swr = (fr & 7) << 4;

#define STAGE(kt_, slot_)                                                       \
  {                                                                             \
    char* ks_ = lds + (slot_)*16384;                                            \
    char* vs_ = ks_ + 8192;                                                     \
    gload16(Kbase + (size_t)(kt_)*8192 + r0 * 128 + s0, ks_ + o0);              \
    gload16(Kbase + (size_t)(kt_)*8192 + r1 * 128 + s1, ks_ + o1);              \
    gload16(Vbase + (size_t)r0 * 2048 + (kt_)*128 + s0, vs_ + o0);              \
    gload16(Vbase + (size_t)r1 * 2048 + (kt_)*128 + s1, vs_ + o1);              \
  }

  STAGE(0, 0);
  STAGE(1, 1);
  for (int kt = 0; kt < 16; kt++) {
    if (kt < 15) WAITV4(); else WAITV0();
    __builtin_amdgcn_s_barrier();
    __builtin_amdgcn_sched_barrier(0);
    if (kt + 2 < 16) STAGE(kt + 2, (kt + 2) % 3);
    const char* ksc = lds + (kt % 3) * 16384;
    const char* vsc = ksc + 8192;
    // S^T = K Q^T : sa[qs][ni] holds S[k = ni*16+fq*4+i][q = fr] (log2 units)
    f32x4 sa[4][4] = {};
    __builtin_amdgcn_s_setprio(1);
#pragma unroll
    for (int ni = 0; ni < 4; ni++) {
      bf16x8 kf0 = *reinterpret_cast<const bf16x8*>(
          ksc + (ni * 16 + fr) * 128 + ((fq * 16) ^ swr));
      bf16x8 kf1 = *reinterpret_cast<const bf16x8*>(
          ksc + (ni * 16 + fr) * 128 + ((64 + fq * 16) ^ swr));
#pragma unroll
      for (int qs = 0; qs < 4; qs++) {
        sa[qs][ni] = mfma16(kf0, qf[qs][0], sa[qs][ni]);
        sa[qs][ni] = mfma16(kf1, qf[qs][1], sa[qs][ni]);
      }
    }
    __builtin_amdgcn_s_setprio(0);
    // p = 2^S in-place (raw v_exp_f32), pack to PV B-frag order
    // pi(kk2,fq,j) = 32*kk2+16*(j>>2)+4*fq+(j&3).
    bf16x8 pb[4][2];
#pragma unroll
    for (int qs = 0; qs < 4; qs++) {
#pragma unroll
      for (int ni = 0; ni < 4; ni++)
#pragma unroll
        for (int i = 0; i < 4; i++)
          sa[qs][ni][i] = __builtin_amdgcn_exp2f(sa[qs][ni][i]);
#pragma unroll
      for (int kk2 = 0; kk2 < 2; kk2++) {
        u32x4 u;
        u[0] = cvtpk(sa[qs][2 * kk2][0], sa[qs][2 * kk2][1]);
        u[1] = cvtpk(sa[qs][2 * kk2][2], sa[qs][2 * kk2][3]);
        u[2] = cvtpk(sa[qs][2 * kk2 + 1][0], sa[qs][2 * kk2 + 1][1]);
        u[3] = cvtpk(sa[qs][2 * kk2 + 1][2], sa[qs][2 * kk2 + 1][3]);
        pb[qs][kk2] = __builtin_bit_cast(bf16x8, u);
      }
      lacc[qs] = mfma16(ones, pb[qs][0], lacc[qs]);
      lacc[qs] = mfma16(ones, pb[qs][1], lacc[qs]);
    }
    // O^T += V^T P  (V A-frag: one b128, permuted order; shared across 4 qs)
    __builtin_amdgcn_s_setprio(1);
#pragma unroll
    for (int nd = 0; nd < 4; nd++) {
      int vrow = (nd * 16 + fr) * 128;
#pragma unroll
      for (int kk2 = 0; kk2 < 2; kk2++) {
        bf16x8 vf = *reinterpret_cast<const bf16x8*>(
            vsc + vrow + ((fq * 32 + kk2 * 16) ^ swr));
#pragma unroll
        for (int qs = 0; qs < 4; qs++)
          oa[qs][nd] = mfma16(vf, pb[qs][kk2], oa[qs][nd]);
      }
    }
    __builtin_amdgcn_s_setprio(0);
  }
  // epilogue: oa[qs][nd]: O^T[d = nd*16+fq*4+i][q = fr], l in lacc[qs][0]
  int b = bh >> 3, hd = bh & 7;
#pragma unroll
  for (int qs = 0; qs < 4; qs++) {
    int q = qt * 256 + qs * 64 + wave * 16 + fr;
    float inv_l = 1.0f / lacc[qs][0];
    __bf16* dst = Res + ((size_t)(b * 1024 + q)) * 512 + hd * 64 + fq * 4;
#pragma unroll
    for (int nd = 0; nd < 4; nd++) {
      bf16x4 ov;
#pragma unroll
      for (int i = 0; i < 4; i++) ov[i] = (__bf16)(oa[qs][nd][i] * inv_l);
      *reinterpret_cast<bf16x4*>(dst + nd * 16) = ov;
    }
  }
#undef STAGE
}

// ---------------- launch ----------------
extern "C" void kernel_launch(void* const* d_in, const int* in_sizes, int n_in,
                              void* d_out, int out_size, void* d_ws, size_t ws_size,
                              hipStream_t stream) {
  const float* x = (const float*)d_in[0];
  const float* wp = (const float*)d_in[1];
  const float* wo = (const float*)d_in[2];
  float* out = (float*)d_out;
  char* w = (char*)d_ws;
  __bf16* wpb = (__bf16*)(w);                    // 1,572,864
  __bf16* wob = (__bf16*)(w + 1572864);          //   524,288
  __bf16* xt = (__bf16*)(w + 2097152);           // 16,777,216
  __bf16* Qb = (__bf16*)(w + 18874368);          // 16,777,216
  __bf16* Kb = (__bf16*)(w + 35651584);          // 16,777,216
  __bf16* Vtb = (__bf16*)(w + 52428800);         // 16,777,216 [bh][d][s-perm]
  __bf16* resb = (__bf16*)(w + 69206016);        // 16,777,216

  transpose_x_k<<<dim3(16, 8, 16), 256, 0, stream>>>(x, xt, wp, wo, wpb, wob);
  gemm_bt_k<2><<<1536, 256, 0, stream>>>(xt, wpb, nullptr, nullptr, Qb, Kb, Vtb);
  attn_k<<<512, 256, 0, stream>>>(Qb, Kb, Vtb, resb);
  gemm_out_k<<<512, 512, 0, stream>>>(wob, resb, out, x);
}

// Round 18
// 114.249 us; speedup vs baseline: 1.0083x; 1.0083x over previous
//
#include <hip/hip_runtime.h>
#include <hip/hip_bf16.h>
#include <math.h>

typedef float f32x4 __attribute__((ext_vector_type(4)));
typedef __bf16 bf16x8 __attribute__((ext_vector_type(8)));
typedef __bf16 bf16x4 __attribute__((ext_vector_type(4)));
typedef unsigned u32x4 __attribute__((ext_vector_type(4)));

#define DEVFN static __device__ __forceinline__

DEVFN void gload16(const void* g, void* l) {
  __builtin_amdgcn_global_load_lds(
      (const __attribute__((address_space(1))) unsigned int*)g,
      (__attribute__((address_space(3))) unsigned int*)l, 16, 0, 0);
}

DEVFN f32x4 mfma16(bf16x8 a, bf16x8 b, f32x4 c) {
  return __builtin_amdgcn_mfma_f32_16x16x32_bf16(a, b, c, 0, 0, 0);
}

DEVFN unsigned cvtpk(float lo, float hi) {
  unsigned r;
  asm("v_cvt_pk_bf16_f32 %0, %1, %2" : "=v"(r) : "v"(lo), "v"(hi));
  return r;
}

#define WAITV4() asm volatile("s_waitcnt vmcnt(4)" ::: "memory")
#define WAITV2() asm volatile("s_waitcnt vmcnt(2)" ::: "memory")
#define WAITV0() asm volatile("s_waitcnt vmcnt(0)" ::: "memory")

// ---- kernel: transpose+cast x [B,C,S] f32 -> xt [B,S,C] bf16, + weight cast --
__global__ __launch_bounds__(256) void transpose_x_k(
    const float* __restrict__ x, __bf16* __restrict__ xt,
    const float* __restrict__ wp, const float* __restrict__ wo,
    __bf16* __restrict__ wpb, __bf16* __restrict__ wob) {
  __shared__ float tile[64][65];
  int b = blockIdx.z, c0 = blockIdx.y * 64, s0 = blockIdx.x * 64;
  int t = threadIdx.x;
  int r = t >> 2, q = (t & 3) << 4;
  const float* src = x + ((size_t)(b * 512 + c0 + r)) * 1024 + s0 + q;
#pragma unroll
  for (int i = 0; i < 4; i++) {
    float4 f = *reinterpret_cast<const float4*>(src + i * 4);
    tile[r][q + i * 4 + 0] = f.x;
    tile[r][q + i * 4 + 1] = f.y;
    tile[r][q + i * 4 + 2] = f.z;
    tile[r][q + i * 4 + 3] = f.w;
  }
  // fused weight cast (independent of the transpose; 2 elems/thread)
  int lid = (blockIdx.z * 8 + blockIdx.y) * 16 + blockIdx.x;  // 0..2047
  int wi = lid * 512 + t * 2;
  if (wi < 786432) {
    float2 f = *reinterpret_cast<const float2*>(wp + wi);
    wpb[wi] = (__bf16)f.x;
    wpb[wi + 1] = (__bf16)f.y;
  } else {
    int j = wi - 786432;
    float2 f = *reinterpret_cast<const float2*>(wo + j);
    wob[j] = (__bf16)f.x;
    wob[j + 1] = (__bf16)f.y;
  }
  __syncthreads();
  bf16x8 o0, o1;
#pragma unroll
  for (int i = 0; i < 8; i++) o0[i] = (__bf16)tile[q + i][r];
#pragma unroll
  for (int i = 0; i < 8; i++) o1[i] = (__bf16)tile[q + 8 + i][r];
  __bf16* dst = xt + ((size_t)(b * 1024 + s0 + r)) * 512 + c0 + q;
  *reinterpret_cast<bf16x8*>(dst) = o0;
  *reinterpret_cast<bf16x8*>(dst + 8) = o1;
}

// ---------------- GEMM1 (QKV): 3-slot rotating pipeline (round-12 verified) ---
// Homogeneous global_load_lds queue; counted vmcnt(4) never 0 mid-loop.
// Stage target (t+2)%3 == (t-1)%3: last touched two barriers ago -> robust to
// compiler scheduling of stores around the barrier (2-slot variant was not:
// r15/r17 intermittent corruption).
template <int MODE>
__global__ __launch_bounds__(256, 4) void gemm_bt_k(
    const __bf16* __restrict__ A, const __bf16* __restrict__ Bt,
    float* __restrict__ Cf, const float* __restrict__ Xres,
    __bf16* __restrict__ Qo, __bf16* __restrict__ Ko, __bf16* __restrict__ Vto) {
  __shared__ __attribute__((aligned(16))) char smem[49152];  // 3 x (A 8K | B 8K)
  int p = blockIdx.x, xcd = p & 7, idx = p >> 3;
  int m0, n0, z;
  if (MODE == 2) {           // 1536 blocks: m 128 panels, n 12
    m0 = (xcd * 16 + idx / 12) * 128;
    n0 = (idx % 12) * 128;
    z = 0;
  } else {                   // 512 blocks: z 16, m 4, n 8
    z = xcd * 2 + idx / 32;
    int rem = idx % 32;
    m0 = (rem >> 3) * 128;
    n0 = (rem & 7) * 128;
    Bt += (size_t)z * (1024L * 512);
  }
  int tid = threadIdx.x, wave = tid >> 6, lane = tid & 63;
  int fr = lane & 15, fq = lane >> 4;
  int wm = (wave >> 1) * 64, wn = (wave & 1) * 64;
  f32x4 acc[4][4] = {};
  int offs[2], rr[2], scc[2];
#pragma unroll
  for (int i = 0; i < 2; i++) {
    offs[i] = wave * 2048 + i * 1024 + lane * 16;  // 0..8191
    rr[i] = offs[i] >> 6;
    scc[i] = (offs[i] & 63) ^ (((rr[i] ^ (rr[i] >> 2)) & 3) << 4);
  }
  int rdsw = (fr ^ (fr >> 2)) & 3;
  const char* Ap = (const char*)A;
  const char* Bp = (const char*)Bt;

#define GSTAGE(k0_, slot_)                                                      \
  {                                                                             \
    char* as_ = smem + (slot_)*16384;                                           \
    char* bs_ = as_ + 8192;                                                     \
    _Pragma("unroll") for (int i = 0; i < 2; i++)                               \
        gload16(Ap + (size_t)(m0 + rr[i]) * 1024 + (k0_)*2 + scc[i],            \
                as_ + offs[i]);                                                 \
    _Pragma("unroll") for (int i = 0; i < 2; i++)                               \
        gload16(Bp + (size_t)(n0 + rr[i]) * 1024 + (k0_)*2 + scc[i],            \
                bs_ + offs[i]);                                                 \
  }

  GSTAGE(0, 0);
  GSTAGE(32, 1);
#pragma unroll
  for (int t = 0; t < 16; t++) {
    if (t < 15) WAITV4(); else WAITV0();
    __builtin_amdgcn_s_barrier();
    __builtin_amdgcn_sched_barrier(0);
    const char* as = smem + (t % 3) * 16384;
    const char* bs = as + 8192;
    bf16x8 af[4], bfr[4];
#pragma unroll
    for (int mi = 0; mi < 4; mi++)
      af[mi] = *reinterpret_cast<const bf16x8*>(
          as + (wm + mi * 16 + fr) * 64 + ((fq ^ rdsw) << 4));
#pragma unroll
    for (int ni = 0; ni < 4; ni++)
      bfr[ni] = *reinterpret_cast<const bf16x8*>(
          bs + (wn + ni * 16 + fr) * 64 + ((fq ^ rdsw) << 4));
    if (t + 2 < 16) GSTAGE((t + 2) * 32, (t + 2) % 3);
    __builtin_amdgcn_s_setprio(1);
#pragma unroll
    for (int mi = 0; mi < 4; mi++)
#pragma unroll
      for (int ni = 0; ni < 4; ni++)
        acc[mi][ni] = mfma16(af[mi], bfr[ni], acc[mi][ni]);
    __builtin_amdgcn_s_setprio(0);
  }
#undef GSTAGE

  if (MODE == 1) {
    float* Co = Cf + (size_t)z * (512L * 1024);
    const float* Xr = Xres + (size_t)z * (512L * 1024);
#pragma unroll
    for (int mi = 0; mi < 4; mi++)
#pragma unroll
      for (int i = 0; i < 4; i++) {
        int row = m0 + wm + mi * 16 + fq * 4 + i;
#pragma unroll
        for (int ni = 0; ni < 4; ni++) {
          size_t idxo = (size_t)row * 1024 + n0 + wn + ni * 16 + fr;
          Co[idxo] = acc[mi][ni][i] + Xr[idxo];
        }
      }
  } else {
    // ---- fused pixnorm epilogue ----
    int g0 = n0 + wn;            // 64-aligned global output-channel base
    int head = g0 / 192;         // 0..7
    int grp = (g0 >> 6) % 3;     // 0=q, 1=k, 2=v
    int b = m0 >> 10, sb = m0 & 1023;
    int bh = b * 8 + head;
    float nrm[4][4];
#pragma unroll
    for (int mi = 0; mi < 4; mi++)
#pragma unroll
      for (int i = 0; i < 4; i++) {
        float ss = 0.f;
#pragma unroll
        for (int ni = 0; ni < 4; ni++) ss += acc[mi][ni][i] * acc[mi][ni][i];
#pragma unroll
        for (int off = 1; off < 16; off <<= 1) ss += __shfl_xor(ss, off);
        float nv = rsqrtf(ss * (1.0f / 64.0f) + 1e-8f);
        // fold SCALE^2 = 1/8 and log2(e) into Q (attention works in exp2 domain)
        if (grp == 0) nv *= 0.18033688011112042f;
        nrm[mi][i] = nv;
      }
    if (grp < 2) {
      __bf16* dst = (grp == 0 ? Qo : Ko) + (size_t)bh * 65536;
#pragma unroll
      for (int mi = 0; mi < 4; mi++)
#pragma unroll
        for (int i = 0; i < 4; i++) {
          int s = sb + wm + mi * 16 + fq * 4 + i;
#pragma unroll
          for (int ni = 0; ni < 4; ni++)
            dst[(size_t)s * 64 + ni * 16 + fr] = (__bf16)(acc[mi][ni][i] * nrm[mi][i]);
        }
    }
    __syncthreads();
    if (grp == 2) {
      // normalized V -> LDS transpose tile [128 s][64 d], 4B-granule XOR swizzle
#pragma unroll
      for (int mi = 0; mi < 4; mi++)
#pragma unroll
        for (int i = 0; i < 4; i++) {
          int r = wm + mi * 16 + fq * 4 + i;
#pragma unroll
          for (int ni = 0; ni < 4; ni++) {
            int col2 = (2 * (ni * 16 + fr)) ^ ((r & 31) << 2);
            *(__bf16*)(smem + r * 128 + col2) = (__bf16)(acc[mi][ni][i] * nrm[mi][i]);
          }
        }
    }
    __syncthreads();
    if (grp == 2) {
      int sl = wm + lane;  // this wave's 64-s half of the 128-s tile
      // permuted k-order within each 64-s tile: k = a*16+f*4+r stored at f*16+a*4+r
      int l = sl & 63;
      int pl = ((l >> 2) & 3) * 16 + (l >> 4) * 4 + (l & 3);
      __bf16* vdst = Vto + (size_t)bh * 65536 + sb + (sl & 64) + pl;
#pragma unroll 8
      for (int d = 0; d < 64; d++) {
        __bf16 v = *(const __bf16*)(smem + sl * 128 + ((2 * d) ^ ((sl & 31) << 2)));
        vdst[(size_t)d * 1024] = v;
      }
    }
  }
}

// ---- GEMM2 (output): 8-wave 512-thread blocks, 128x128 tile, 2-slot vmcnt(2) -
__global__ __launch_bounds__(512, 4) void gemm_out_k(
    const __bf16* __restrict__ A, const __bf16* __restrict__ Bt,
    float* __restrict__ Cf, const float* __restrict__ Xres) {
  __shared__ __attribute__((aligned(16))) char smem[32768];  // 2 x (A 8K | B 8K)
  const int K = 512;
  int p = blockIdx.x, xcd = p & 7, idx = p >> 3;
  int z = xcd * 2 + idx / 32;
  int rem = idx % 32;
  int m0 = (rem >> 3) * 128;
  int n0 = (rem & 7) * 128;
  Bt += (size_t)z * (1024L * 512);
  int tid = threadIdx.x, wave = tid >> 6, lane = tid & 63;
  int fr = lane & 15, fq = lane >> 4;
  int wm = (wave >> 2) * 64, wn = (wave & 3) * 32;
  f32x4 acc[4][2] = {};
  int offs = tid * 16;           // 0..8191
  int rr = offs >> 6;
  int scc = (offs & 63) ^ (((rr ^ (rr >> 2)) & 3) << 4);
  int rdsw = (fr ^ (fr >> 2)) & 3;
  const char* Ap = (const char*)A;
  const char* Bp = (const char*)Bt;

#define GSTAGE2(k0_, slot_)                                                     \
  {                                                                             \
    char* as_ = smem + (slot_)*16384;                                           \
    gload16(Ap + (size_t)(m0 + rr) * 1024 + (k0_)*2 + scc, as_ + offs);         \
    gload16(Bp + (size_t)(n0 + rr) * 1024 + (k0_)*2 + scc, as_ + 8192 + offs);  \
  }

  GSTAGE2(0, 0);
  GSTAGE2(32, 1);
  int cur = 0;
  for (int k0 = 0; k0 < K; k0 += 32) {
    if (k0 + 32 < K) WAITV2(); else WAITV0();
    __builtin_amdgcn_s_barrier();
    __builtin_amdgcn_sched_barrier(0);
    const char* as = smem + cur * 16384;
    const char* bs = as + 8192;
    bf16x8 af[4], bfr[2];
#pragma unroll
    for (int mi = 0; mi < 4; mi++)
      af[mi] = *reinterpret_cast<const bf16x8*>(
          as + (wm + mi * 16 + fr) * 64 + ((fq ^ rdsw) << 4));
#pragma unroll
    for (int ni = 0; ni < 2; ni++)
      bfr[ni] = *reinterpret_cast<const bf16x8*>(
          bs + (wn + ni * 16 + fr) * 64 + ((fq ^ rdsw) << 4));
    __builtin_amdgcn_s_setprio(1);
#pragma unroll
    for (int mi = 0; mi < 4; mi++)
#pragma unroll
      for (int ni = 0; ni < 2; ni++)
        acc[mi][ni] = mfma16(af[mi], bfr[ni], acc[mi][ni]);
    __builtin_amdgcn_s_setprio(0);
    __builtin_amdgcn_s_barrier();   // all waves done reading slot cur
    if (k0 + 64 < K) GSTAGE2(k0 + 64, cur);
    cur ^= 1;
  }
#undef GSTAGE2

  float* Co = Cf + (size_t)z * (512L * 1024);
  const float* Xr = Xres + (size_t)z * (512L * 1024);
#pragma unroll
  for (int mi = 0; mi < 4; mi++)
#pragma unroll
    for (int i = 0; i < 4; i++) {
      int row = m0 + wm + mi * 16 + fq * 4 + i;
#pragma unroll
      for (int ni = 0; ni < 2; ni++) {
        size_t idxo = (size_t)row * 1024 + n0 + wn + ni * 16 + fr;
        Co[idxo] = acc[mi][ni][i] + Xr[idxo];
      }
    }
}

// ------------- flash attention: QBLK=256 (4 q-sets/wave), 3-slot pipeline -----
__global__ __launch_bounds__(256, 2) void attn_k(const __bf16* __restrict__ Q,
                                                 const __bf16* __restrict__ Kb,
                                                 const __bf16* __restrict__ Vt,
                                                 __bf16* __restrict__ Res) {
  __shared__ __attribute__((aligned(16))) char lds[49152];  // 3 x (K 8K | V 8K)
  int p = blockIdx.x;                    // 512 = 128 bh * 4 qt
  int v = (p & 7) * 64 + (p >> 3);       // XCD cluster: 16 bh per XCD (KV 4MB L2)
  int qt = v & 3, bh = v >> 2;
  int wave = threadIdx.x >> 6, lane = threadIdx.x & 63;
  int fr = lane & 15, fq = lane >> 4;
  const __bf16* Qb = Q + (size_t)bh * 65536;
  const char* Kbase = (const char*)(Kb + (size_t)bh * 65536);
  const char* Vbase = (const char*)(Vt + (size_t)bh * 65536);
  bf16x8 qf[4][2];
#pragma unroll
  for (int qs = 0; qs < 4; qs++)
#pragma unroll
    for (int kk = 0; kk < 2; kk++)
      qf[qs][kk] = *reinterpret_cast<const bf16x8*>(
          Qb + (size_t)(qt * 256 + qs * 64 + wave * 16 + fr) * 64 + kk * 32 + fq * 8);

  bf16x8 ones;
#pragma unroll
  for (int j = 0; j < 8; j++) ones[j] = (__bf16)1.0f;

  f32x4 oa[4][4] = {};
  f32x4 lacc[4] = {};

  int o0 = wave * 2048 + lane * 16;
  int o1 = o0 + 1024;
  int r0 = o0 >> 7, c0 = o0 & 127, r1 = o1 >> 7, c1 = o1 & 127;
  int s0 = c0 ^ ((r0 & 7) << 4), s1 = c1 ^ ((r1 & 7) << 4);
  int swr = (fr & 7) << 4;

#define STAGE(kt_, slot_)                                                       \
  {                                                                             \
    char* ks_ = lds + (slot_)*16384;                                            \
    char* vs_ = ks_ + 8192;                                                     \
    gload16(Kbase + (size_t)(kt_)*8192 + r0 * 128 + s0, ks_ + o0);              \
    gload16(Kbase + (size_t)(kt_)*8192 + r1 * 128 + s1, ks_ + o1);              \
    gload16(Vbase + (size_t)r0 * 2048 + (kt_)*128 + s0, vs_ + o0);              \
    gload16(Vbase + (size_t)r1 * 2048 + (kt_)*128 + s1, vs_ + o1);              \
  }

  STAGE(0, 0);
  STAGE(1, 1);
  for (int kt = 0; kt < 16; kt++) {
    if (kt < 15) WAITV4(); else WAITV0();
    __builtin_amdgcn_s_barrier();
    __builtin_amdgcn_sched_barrier(0);
    if (kt + 2 < 16) STAGE(kt + 2, (kt + 2) % 3);
    const char* ksc = lds + (kt % 3) * 16384;
    const char* vsc = ksc + 8192;
    // S^T = K Q^T : sa[qs][ni] holds S[k = ni*16+fq*4+i][q = fr] (log2 units)
    f32x4 sa[4][4] = {};
    __builtin_amdgcn_s_setprio(1);
#pragma unroll
    for (int ni = 0; ni < 4; ni++) {
      bf16x8 kf0 = *reinterpret_cast<const bf16x8*>(
          ksc + (ni * 16 + fr) * 128 + ((fq * 16) ^ swr));
      bf16x8 kf1 = *reinterpret_cast<const bf16x8*>(
          ksc + (ni * 16 + fr) * 128 + ((64 + fq * 16) ^ swr));
#pragma unroll
      for (int qs = 0; qs < 4; qs++) {
        sa[qs][ni] = mfma16(kf0, qf[qs][0], sa[qs][ni]);
        sa[qs][ni] = mfma16(kf1, qf[qs][1], sa[qs][ni]);
      }
    }
    __builtin_amdgcn_s_setprio(0);
    // p = 2^S in-place (raw v_exp_f32), pack to PV B-frag order
    // pi(kk2,fq,j) = 32*kk2+16*(j>>2)+4*fq+(j&3).
    bf16x8 pb[4][2];
#pragma unroll
    for (int qs = 0; qs < 4; qs++) {
#pragma unroll
      for (int ni = 0; ni < 4; ni++)
#pragma unroll
        for (int i = 0; i < 4; i++)
          sa[qs][ni][i] = __builtin_amdgcn_exp2f(sa[qs][ni][i]);
#pragma unroll
      for (int kk2 = 0; kk2 < 2; kk2++) {
        u32x4 u;
        u[0] = cvtpk(sa[qs][2 * kk2][0], sa[qs][2 * kk2][1]);
        u[1] = cvtpk(sa[qs][2 * kk2][2], sa[qs][2 * kk2][3]);
        u[2] = cvtpk(sa[qs][2 * kk2 + 1][0], sa[qs][2 * kk2 + 1][1]);
        u[3] = cvtpk(sa[qs][2 * kk2 + 1][2], sa[qs][2 * kk2 + 1][3]);
        pb[qs][kk2] = __builtin_bit_cast(bf16x8, u);
      }
      lacc[qs] = mfma16(ones, pb[qs][0], lacc[qs]);
      lacc[qs] = mfma16(ones, pb[qs][1], lacc[qs]);
    }
    // O^T += V^T P  (V A-frag: one b128, permuted order; shared across 4 qs)
    __builtin_amdgcn_s_setprio(1);
#pragma unroll
    for (int nd = 0; nd < 4; nd++) {
      int vrow = (nd * 16 + fr) * 128;
#pragma unroll
      for (int kk2 = 0; kk2 < 2; kk2++) {
        bf16x8 vf = *reinterpret_cast<const bf16x8*>(
            vsc + vrow + ((fq * 32 + kk2 * 16) ^ swr));
#pragma unroll
        for (int qs = 0; qs < 4; qs++)
          oa[qs][nd] = mfma16(vf, pb[qs][kk2], oa[qs][nd]);
      }
    }
    __builtin_amdgcn_s_setprio(0);
  }
  // epilogue: oa[qs][nd]: O^T[d = nd*16+fq*4+i][q = fr], l in lacc[qs][0]
  int b = bh >> 3, hd = bh & 7;
#pragma unroll
  for (int qs = 0; qs < 4; qs++) {
    int q = qt * 256 + qs * 64 + wave * 16 + fr;
    float inv_l = 1.0f / lacc[qs][0];
    __bf16* dst = Res + ((size_t)(b * 1024 + q)) * 512 + hd * 64 + fq * 4;
#pragma unroll
    for (int nd = 0; nd < 4; nd++) {
      bf16x4 ov;
#pragma unroll
      for (int i = 0; i < 4; i++) ov[i] = (__bf16)(oa[qs][nd][i] * inv_l);
      *reinterpret_cast<bf16x4*>(dst + nd * 16) = ov;
    }
  }
#undef STAGE
}

// ---------------- launch ----------------
extern "C" void kernel_launch(void* const* d_in, const int* in_sizes, int n_in,
                              void* d_out, int out_size, void* d_ws, size_t ws_size,
                              hipStream_t stream) {
  const float* x = (const float*)d_in[0];
  const float* wp = (const float*)d_in[1];
  const float* wo = (const float*)d_in[2];
  float* out = (float*)d_out;
  char* w = (char*)d_ws;
  __bf16* wpb = (__bf16*)(w);                    // 1,572,864
  __bf16* wob = (__bf16*)(w + 1572864);          //   524,288
  __bf16* xt = (__bf16*)(w + 2097152);           // 16,777,216
  __bf16* Qb = (__bf16*)(w + 18874368);          // 16,777,216
  __bf16* Kb = (__bf16*)(w + 35651584);          // 16,777,216
  __bf16* Vtb = (__bf16*)(w + 52428800);         // 16,777,216 [bh][d][s-perm]
  __bf16* resb = (__bf16*)(w + 69206016);        // 16,777,216

  transpose_x_k<<<dim3(16, 8, 16), 256, 0, stream>>>(x, xt, wp, wo, wpb, wob);
  gemm_bt_k<2><<<1536, 256, 0, stream>>>(xt, wpb, nullptr, nullptr, Qb, Kb, Vtb);
  attn_k<<<512, 256, 0, stream>>>(Qb, Kb, Vtb, resb);
  gemm_out_k<<<512, 512, 0, stream>>>(wob, resb, out, x);
}